// Round 6
// baseline (256.753 us; speedup 1.0000x reference)
//
#include <hip/hip_runtime.h>

#define NBINS 10
#define TPB 256
#define NCOPY 32
#define CSTR 17                      // 17*c mod 32 is a bank bijection
#define LDSN (NCOPY * CSTR)          // 544 ints
#define SCALE 1048576.0f             // 2^20 fixed-point scale
#define INV_SCALE (1.0 / 1048576.0)  // double, used once in finalize
#define NB 2048                      // 8 blocks/CU

// d_ws layout: [0..9] int64 bin accumulators, [10] (as int) ticket counter.
// kernel_launch zeroes the first 128 bytes with hipMemsetAsync each call.

__global__ __launch_bounds__(TPB) void uce_hist(const float* __restrict__ up,
                                                const float* __restrict__ ep,
                                                unsigned long long* __restrict__ acc,
                                                int* __restrict__ ticket,
                                                float* __restrict__ out,
                                                int n4, float inv_n) {
    __shared__ int h[LDSN];
    int tid = threadIdx.x;
    for (int i = tid; i < LDSN; i += TPB) h[i] = 0;
    __syncthreads();

    int cbase = (tid & (NCOPY - 1)) * CSTR;

    auto proc1 = [&](float u, float e) {
        // FROZEN binning (bit-exact vs reference, absmax 0.0 in R0-R4):
        // bin i iff fl(i*0.1f) < u <= fl((i+1)*0.1f)
        int g = (int)(u * 10.0f);
        g = g > 9 ? 9 : g;
        float gf = (float)g;
        float lo = gf * 0.1f;
        float hi = (gf + 1.0f) * 0.1f;
        g += (u > hi) ? 1 : 0;             // mutually exclusive fixups
        g -= (u <= lo) ? 1 : 0;            // u<=0 -> -1; u>1 -> 10
        int slot = g & 15;                 // -1->15, 10->10: scratch, never read
        int v = (int)rintf((u - e) * SCALE);
        atomicAdd(&h[cbase + slot], v);    // ds_add_u32, no return -> no stall
    };
    auto proc4 = [&](float4 uu, float4 ee) {
        proc1(uu.x, ee.x); proc1(uu.y, ee.y);
        proc1(uu.z, ee.z); proc1(uu.w, ee.w);
    };

    const float4* __restrict__ u4 = (const float4*)up;
    const float4* __restrict__ e4 = (const float4*)ep;
    int base = blockIdx.x * TPB + tid;
    int T = gridDim.x * TPB;
    int nb = n4 / (4 * T);               // full 8-load batches (exact at N=2^25)

    for (int it = 0; it < nb; ++it) {
        int i0 = base + it * 4 * T;
        float4 ua = u4[i0], ub = u4[i0 + T], uc = u4[i0 + 2 * T], ud = u4[i0 + 3 * T];
        float4 ea = e4[i0], eb = e4[i0 + T], ec = e4[i0 + 2 * T], ed = e4[i0 + 3 * T];
        proc4(ua, ea); proc4(ub, eb); proc4(uc, ec); proc4(ud, ed);
    }
    for (int i = base + nb * 4 * T; i < n4; i += T) {   // tail (empty at N=2^25)
        proc4(u4[i], e4[i]);
    }
    __syncthreads();

    // Per-block bin sum -> global int64 accumulator (exact, order-independent).
    if (tid < NBINS) {
        int s = 0;
#pragma unroll
        for (int c = 0; c < NCOPY; ++c) s += h[c * CSTR + tid];
        atomicAdd(&acc[tid], (unsigned long long)(long long)s);  // sign-extend
    }
    __syncthreads();                     // compiler drains vmcnt before barrier
    __threadfence();

    // Last-block-done finalize: UCE = (1/n) * sum_b |S_b|
    __shared__ int amlast;
    if (tid == 0) amlast = atomicAdd(ticket, 1);
    __syncthreads();
    if (amlast == NB - 1 && tid == 0) {
        double uce = 0.0;
#pragma unroll
        for (int b = 0; b < NBINS; ++b) {
            long long v = (long long)atomicAdd(&acc[b], 0ull);  // coherent read
            double sb = (double)v * INV_SCALE;
            uce += sb < 0.0 ? -sb : sb;
        }
        out[0] = (float)(uce * (double)inv_n);
    }
}

extern "C" void kernel_launch(void* const* d_in, const int* in_sizes, int n_in,
                              void* d_out, int out_size, void* d_ws, size_t ws_size,
                              hipStream_t stream) {
    const float* u = (const float*)d_in[0];
    const float* e = (const float*)d_in[1];
    unsigned long long* acc = (unsigned long long*)d_ws;   // 10 x i64
    int* ticket = (int*)((char*)d_ws + NBINS * sizeof(unsigned long long));
    float* out = (float*)d_out;
    int n = in_sizes[0];
    int n4 = n >> 2;

    hipMemsetAsync(d_ws, 0, 128, stream);   // zero accumulators + ticket
    uce_hist<<<NB, TPB, 0, stream>>>(u, e, acc, ticket, out, n4, 1.0f / (float)n);
}

// Round 7
// 52.919 us; speedup vs baseline: 4.8518x; 4.8518x over previous
//
#include <hip/hip_runtime.h>

#define NBINS 10
#define TPB 256
#define NCOPY 32
#define CSTR 17                      // 17*c mod 32 is a bank bijection
#define LDSN (NCOPY * CSTR)          // 544 ints
#define SCALE 1048576.0f             // 2^20 fixed-point scale
#define INV_SCALE (1.0f / 1048576.0f)

// Pass 1: histogram of fixed-point d = u-e into per-block LDS (native
// ds_add_u32 fire-and-forget atomics), per-block float partials -> part[].
// (R3 structure, proven 51.4 us / absmax 0.0. R4 MLP-pinning: neutral.
//  R5 single-kernel fusion w/ threadfence+ticket: 5x regression. Reverted.)
__global__ __launch_bounds__(TPB) void uce_hist(const float* __restrict__ up,
                                                const float* __restrict__ ep,
                                                float* __restrict__ part, int n4) {
    __shared__ int h[LDSN];
    int tid = threadIdx.x;
    for (int i = tid; i < LDSN; i += TPB) h[i] = 0;
    __syncthreads();

    int cbase = (tid & (NCOPY - 1)) * CSTR;

    auto proc1 = [&](float u, float e) {
        // FROZEN binning (bit-exact vs reference, absmax 0.0 in R0-R6):
        // bin i iff fl(i*0.1f) < u <= fl((i+1)*0.1f)
        int g = (int)(u * 10.0f);
        g = g > 9 ? 9 : g;
        float gf = (float)g;
        float lo = gf * 0.1f;
        float hi = (gf + 1.0f) * 0.1f;
        g += (u > hi) ? 1 : 0;             // mutually exclusive fixups
        g -= (u <= lo) ? 1 : 0;            // u<=0 -> -1; u>1 -> 10
        int slot = g & 15;                 // -1->15, 10->10: scratch, never read
        int v = (int)rintf((u - e) * SCALE);
        atomicAdd(&h[cbase + slot], v);    // ds_add_u32, no return -> no stall
    };
    auto proc4 = [&](float4 uu, float4 ee) {
        proc1(uu.x, ee.x); proc1(uu.y, ee.y);
        proc1(uu.z, ee.z); proc1(uu.w, ee.w);
    };

    const float4* __restrict__ u4 = (const float4*)up;
    const float4* __restrict__ e4 = (const float4*)ep;
    int base = blockIdx.x * TPB + tid;
    int T = gridDim.x * TPB;
    int nb = n4 / (4 * T);               // full 8-load batches (exact at N=2^25)

    for (int it = 0; it < nb; ++it) {
        int i0 = base + it * 4 * T;
        float4 ua = u4[i0], ub = u4[i0 + T], uc = u4[i0 + 2 * T], ud = u4[i0 + 3 * T];
        float4 ea = e4[i0], eb = e4[i0 + T], ec = e4[i0 + 2 * T], ed = e4[i0 + 3 * T];
        proc4(ua, ea); proc4(ub, eb); proc4(uc, ec); proc4(ud, ed);
    }
    for (int i = base + nb * 4 * T; i < n4; i += T) {   // tail (empty at N=2^25)
        proc4(u4[i], e4[i]);
    }
    __syncthreads();

    if (tid < NBINS) {
        int s = 0;
#pragma unroll
        for (int c = 0; c < NCOPY; ++c) s += h[c * CSTR + tid];
        part[blockIdx.x * NBINS + tid] = (float)s * INV_SCALE;
    }
}

// Pass 2: reduce per-block partials, UCE = (1/n) * sum_b |S_b|
__global__ __launch_bounds__(TPB) void uce_final(const float* __restrict__ part,
                                                 float* __restrict__ out,
                                                 int nblocks, float inv_n) {
    float s[NBINS];
#pragma unroll
    for (int b = 0; b < NBINS; ++b) s[b] = 0.0f;
    int tid = threadIdx.x;
    for (int j = tid; j < nblocks; j += TPB) {
        const float* p = part + j * NBINS;
#pragma unroll
        for (int b = 0; b < NBINS; ++b) s[b] += p[b];
    }
#pragma unroll
    for (int b = 0; b < NBINS; ++b) {
#pragma unroll
        for (int off = 32; off > 0; off >>= 1) s[b] += __shfl_down(s[b], off, 64);
    }
    __shared__ float sm[4][NBINS];
    int w = tid >> 6, lane = tid & 63;
    if (lane == 0) {
#pragma unroll
        for (int b = 0; b < NBINS; ++b) sm[w][b] = s[b];
    }
    __syncthreads();
    if (tid == 0) {
        float uce = 0.0f;
#pragma unroll
        for (int b = 0; b < NBINS; ++b) {
            float t = sm[0][b] + sm[1][b] + sm[2][b] + sm[3][b];
            uce += fabsf(t);
        }
        out[0] = uce * inv_n;
    }
}

extern "C" void kernel_launch(void* const* d_in, const int* in_sizes, int n_in,
                              void* d_out, int out_size, void* d_ws, size_t ws_size,
                              hipStream_t stream) {
    const float* u = (const float*)d_in[0];
    const float* e = (const float*)d_in[1];
    float* part = (float*)d_ws;          // 2048*10 floats = 80 KB scratch
    float* out = (float*)d_out;
    int n = in_sizes[0];
    int n4 = n >> 2;
    const int NB = 2048;                 // 8 blocks/CU

    uce_hist<<<NB, TPB, 0, stream>>>(u, e, part, n4);
    uce_final<<<1, TPB, 0, stream>>>(part, out, NB, 1.0f / (float)n);
}

// Round 8
// 51.679 us; speedup vs baseline: 4.9683x; 1.0240x over previous
//
#include <hip/hip_runtime.h>

#define NBINS 10
#define TPB 256
#define NCOPY 64                     // one private copy per lane: no same-addr collisions
#define CSTR 17                      // 17*c mod 32 covers each bank exactly 2x (free)
#define LDSN (NCOPY * CSTR)          // 1088 ints = 4352 B
#define SCALE 1048576.0f             // 2^20 fixed-point scale
#define INV_SCALE (1.0f / 1048576.0f)
#define NB 2048                      // 8 blocks/CU

// Pass 1: histogram of fixed-point d = u-e into per-lane LDS columns (native
// ds_add_u32 fire-and-forget atomics), per-block partials -> part[] bin-major.
// (R3 structure, proven 51-53 us / absmax 0.0. R4 MLP-pinning: neutral.
//  R5 single-kernel fusion w/ threadfence+ticket: 5x regression. Reverted.)
__global__ __launch_bounds__(TPB) void uce_hist(const float* __restrict__ up,
                                                const float* __restrict__ ep,
                                                float* __restrict__ part, int n4) {
    __shared__ int h[LDSN];
    int tid = threadIdx.x;
    for (int i = tid; i < LDSN; i += TPB) h[i] = 0;
    __syncthreads();

    int cbase = (tid & (NCOPY - 1)) * CSTR;

    auto proc1 = [&](float u, float e) {
        // FROZEN binning (bit-exact vs reference, absmax 0.0 in R0-R6):
        // bin i iff fl(i*0.1f) < u <= fl((i+1)*0.1f)
        int g = (int)(u * 10.0f);
        g = g > 9 ? 9 : g;
        float gf = (float)g;
        float lo = gf * 0.1f;
        float hi = (gf + 1.0f) * 0.1f;
        g += (u > hi) ? 1 : 0;             // mutually exclusive fixups
        g -= (u <= lo) ? 1 : 0;            // u<=0 -> -1; u>1 -> 10
        int slot = g & 15;                 // -1->15, 10->10: scratch, never read
        int v = (int)rintf((u - e) * SCALE);
        atomicAdd(&h[cbase + slot], v);    // ds_add_u32, no return -> no stall
    };
    auto proc4 = [&](float4 uu, float4 ee) {
        proc1(uu.x, ee.x); proc1(uu.y, ee.y);
        proc1(uu.z, ee.z); proc1(uu.w, ee.w);
    };

    const float4* __restrict__ u4 = (const float4*)up;
    const float4* __restrict__ e4 = (const float4*)ep;
    int base = blockIdx.x * TPB + tid;
    int T = gridDim.x * TPB;
    int nb = n4 / (4 * T);               // full 8-load batches (exact at N=2^25)

    for (int it = 0; it < nb; ++it) {
        int i0 = base + it * 4 * T;
        float4 ua = u4[i0], ub = u4[i0 + T], uc = u4[i0 + 2 * T], ud = u4[i0 + 3 * T];
        float4 ea = e4[i0], eb = e4[i0 + T], ec = e4[i0 + 2 * T], ed = e4[i0 + 3 * T];
        proc4(ua, ea); proc4(ub, eb); proc4(uc, ec); proc4(ud, ed);
    }
    for (int i = base + nb * 4 * T; i < n4; i += T) {   // tail (empty at N=2^25)
        proc4(u4[i], e4[i]);
    }
    __syncthreads();

    // Bin-major partials: finalize reads each bin's 2048 partials coalesced.
    if (tid < NBINS) {
        int s = 0;
#pragma unroll
        for (int c = 0; c < NCOPY; ++c) s += h[c * CSTR + tid];
        part[tid * NB + blockIdx.x] = (float)s * INV_SCALE;
    }
}

// Pass 2: UCE = (1/n) * sum_b |S_b|; bin-major float4 reads.
__global__ __launch_bounds__(TPB) void uce_final(const float* __restrict__ part,
                                                 float* __restrict__ out,
                                                 float inv_n) {
    float s[NBINS];
#pragma unroll
    for (int b = 0; b < NBINS; ++b) s[b] = 0.0f;
    int tid = threadIdx.x;
    const float4* p4 = (const float4*)part;          // NB % 4 == 0
    for (int j = tid; j < NB / 4; j += TPB) {
#pragma unroll
        for (int b = 0; b < NBINS; ++b) {
            float4 v = p4[b * (NB / 4) + j];
            s[b] += (v.x + v.y) + (v.z + v.w);
        }
    }
#pragma unroll
    for (int b = 0; b < NBINS; ++b) {
#pragma unroll
        for (int off = 32; off > 0; off >>= 1) s[b] += __shfl_down(s[b], off, 64);
    }
    __shared__ float sm[4][NBINS];
    int w = tid >> 6, lane = tid & 63;
    if (lane == 0) {
#pragma unroll
        for (int b = 0; b < NBINS; ++b) sm[w][b] = s[b];
    }
    __syncthreads();
    if (tid == 0) {
        float uce = 0.0f;
#pragma unroll
        for (int b = 0; b < NBINS; ++b) {
            float t = sm[0][b] + sm[1][b] + sm[2][b] + sm[3][b];
            uce += fabsf(t);
        }
        out[0] = uce * inv_n;
    }
}

extern "C" void kernel_launch(void* const* d_in, const int* in_sizes, int n_in,
                              void* d_out, int out_size, void* d_ws, size_t ws_size,
                              hipStream_t stream) {
    const float* u = (const float*)d_in[0];
    const float* e = (const float*)d_in[1];
    float* part = (float*)d_ws;          // 10*2048 floats = 80 KB scratch
    float* out = (float*)d_out;
    int n = in_sizes[0];
    int n4 = n >> 2;

    uce_hist<<<NB, TPB, 0, stream>>>(u, e, part, n4);
    uce_final<<<1, TPB, 0, stream>>>(part, out, 1.0f / (float)n);
}